// Round 1
// baseline (563.666 us; speedup 1.0000x reference)
//
#include <hip/hip_runtime.h>

// Trilinear grid interpolation:
//   velocity: [B, 3, G, G, G] f32, points: [B, N, 3] f32, bb: [3,2] f32
//   out: [B, N, 3] f32
// G is fixed at 128 by the harness's setup_inputs (also required host-side to
// derive B and N from flat in_sizes).

constexpr int G = 128;
constexpr long long G3 = (long long)G * G * G;

__global__ __launch_bounds__(256) void trilerp_kernel(
    const float* __restrict__ vel,   // [B,3,G,G,G]
    const float* __restrict__ pts,   // [B,N,3]
    const float* __restrict__ bb,    // [3,2]
    float* __restrict__ out,         // [B,N,3]
    int B, int N)
{
    int tid = blockIdx.x * blockDim.x + threadIdx.x;
    if (tid >= B * N) return;
    int b = tid / N;

    // bounding box (L1/L2-resident after first wave)
    float bx0 = bb[0], bx1 = bb[1];
    float by0 = bb[2], by1 = bb[3];
    float bz0 = bb[4], bz1 = bb[5];

    const float* p = pts + (long long)tid * 3;
    float px = p[0], py = p[1], pz = p[2];

    const float Gm1 = (float)(G - 1);
    float u = (px - bx0) / (bx1 - bx0) * Gm1;
    float v = (py - by0) / (by1 - by0) * Gm1;
    float w = (pz - bz0) / (bz1 - bz0) * Gm1;

    // match reference numerics exactly:
    // f1 = clip(floor(uvw), 0, G-1); frac = uvw - f1; gfrac = f1 + 1 - uvw
    float fu = fminf(fmaxf(floorf(u), 0.f), Gm1);
    float fv = fminf(fmaxf(floorf(v), 0.f), Gm1);
    float fw = fminf(fmaxf(floorf(w), 0.f), Gm1);

    float du = u - fu, dv = v - fv, dw = w - fw;       // frac
    float gu = fu + 1.0f - u;                          // gfrac
    float gv = fv + 1.0f - v;
    float gw = fw + 1.0f - w;

    int iu1 = (int)fu, iv1 = (int)fv, iw1 = (int)fw;
    int iu2 = min(iu1 + 1, G - 1);
    int iv2 = min(iv1 + 1, G - 1);
    int iw2 = min(iw1 + 1, G - 1);

    float w11 = gu * gv, w12 = gu * dv, w21 = du * gv, w22 = du * dv;

    const float* vb = vel + (long long)b * 3 * G3;

    float o[3];
    #pragma unroll
    for (int c = 0; c < 3; ++c) {
        const float* vc = vb + (long long)c * G3;
        const float* r11 = vc + ((iu1 << 7) + iv1) * G;  // G=128
        const float* r12 = vc + ((iu1 << 7) + iv2) * G;
        const float* r21 = vc + ((iu2 << 7) + iv1) * G;
        const float* r22 = vc + ((iu2 << 7) + iv2) * G;
        o[c] = w11 * (gw * r11[iw1] + dw * r11[iw2])
             + w12 * (gw * r12[iw1] + dw * r12[iw2])
             + w21 * (gw * r21[iw1] + dw * r21[iw2])
             + w22 * (gw * r22[iw1] + dw * r22[iw2]);
    }

    float* op = out + (long long)tid * 3;
    op[0] = o[0]; op[1] = o[1]; op[2] = o[2];
}

extern "C" void kernel_launch(void* const* d_in, const int* in_sizes, int n_in,
                              void* d_out, int out_size, void* d_ws, size_t ws_size,
                              hipStream_t stream) {
    const float* vel = (const float*)d_in[0];
    const float* pts = (const float*)d_in[1];
    const float* bb  = (const float*)d_in[2];
    // d_in[3] is grid_size (==128, hard-coded as constexpr G above)
    float* out = (float*)d_out;

    int B = (int)(in_sizes[0] / (3 * G3));       // 16
    int N = in_sizes[1] / (3 * B);               // 200000

    int total = B * N;
    int block = 256;
    int grid = (total + block - 1) / block;
    trilerp_kernel<<<grid, block, 0, stream>>>(vel, pts, bb, out, B, N);
}

// Round 2
// 348.670 us; speedup vs baseline: 1.6166x; 1.6166x over previous
//
#include <hip/hip_runtime.h>

// Trilinear grid interpolation, XCD-slab partitioned.
//   velocity: [B, 3, G, G, G] f32, points: [B, N, 3] f32, bb: [3,2] f32
//   out: [B, N, 3] f32
//
// Key idea: the gather target (24 MB/batch) can't fit a 4 MB per-XCD L2 when
// every XCD gathers uniformly. Partition u into 8 slabs of 16 planes
// (3 MB/slab). blockIdx%8 round-robins across XCDs on MI355X, so slab s's
// blocks land on XCD s: each XCD keeps only its slab resident in L2.
// Every slab-block scans the whole point chunk but gathers/writes only points
// it owns (iu1>>4 == slab) -> each point written exactly once.

constexpr int G = 128;
constexpr long long G3 = (long long)G * G * G;
constexpr int NSLAB = 8;   // == #XCDs

__global__ __launch_bounds__(256) void trilerp_slab_kernel(
    const float* __restrict__ vel,   // [B,3,G,G,G]
    const float* __restrict__ pts,   // [B,N,3]
    const float* __restrict__ bb,    // [3,2]
    float* __restrict__ out,         // [B,N,3]
    int N, int nchunk)
{
    int bid  = blockIdx.x;
    int slab = bid & (NSLAB - 1);
    int t    = bid >> 3;
    int c    = t % nchunk;           // chunk within batch
    int b    = t / nchunk;           // batch

    int n = c * 256 + threadIdx.x;
    if (n >= N) return;

    float bx0 = bb[0], bx1 = bb[1];
    float by0 = bb[2], by1 = bb[3];
    float bz0 = bb[4], bz1 = bb[5];

    long long pi = (long long)b * N + n;
    const float* p = pts + pi * 3;
    float px = p[0], py = p[1], pz = p[2];

    const float Gm1 = (float)(G - 1);
    float u = (px - bx0) / (bx1 - bx0) * Gm1;

    float fu = fminf(fmaxf(floorf(u), 0.f), Gm1);
    int iu1 = (int)fu;
    if ((iu1 >> 4) != slab) return;   // not this XCD's slab

    float v = (py - by0) / (by1 - by0) * Gm1;
    float w = (pz - bz0) / (bz1 - bz0) * Gm1;
    float fv = fminf(fmaxf(floorf(v), 0.f), Gm1);
    float fw = fminf(fmaxf(floorf(w), 0.f), Gm1);

    float du = u - fu, dv = v - fv, dw = w - fw;   // frac
    float gu = fu + 1.0f - u;                      // gfrac
    float gv = fv + 1.0f - v;
    float gw = fw + 1.0f - w;

    int iv1 = (int)fv, iw1 = (int)fw;
    int iu2 = min(iu1 + 1, G - 1);
    int iv2 = min(iv1 + 1, G - 1);
    int iw2 = min(iw1 + 1, G - 1);

    float w11 = gu * gv, w12 = gu * dv, w21 = du * gv, w22 = du * dv;

    const float* vb = vel + (long long)b * 3 * G3;

    float o[3];
    #pragma unroll
    for (int ch = 0; ch < 3; ++ch) {
        const float* vc = vb + (long long)ch * G3;
        const float* r11 = vc + ((iu1 << 7) + iv1) * G;
        const float* r12 = vc + ((iu1 << 7) + iv2) * G;
        const float* r21 = vc + ((iu2 << 7) + iv1) * G;
        const float* r22 = vc + ((iu2 << 7) + iv2) * G;
        o[ch] = w11 * (gw * r11[iw1] + dw * r11[iw2])
              + w12 * (gw * r12[iw1] + dw * r12[iw2])
              + w21 * (gw * r21[iw1] + dw * r21[iw2])
              + w22 * (gw * r22[iw1] + dw * r22[iw2]);
    }

    float* op = out + pi * 3;
    op[0] = o[0]; op[1] = o[1]; op[2] = o[2];
}

extern "C" void kernel_launch(void* const* d_in, const int* in_sizes, int n_in,
                              void* d_out, int out_size, void* d_ws, size_t ws_size,
                              hipStream_t stream) {
    const float* vel = (const float*)d_in[0];
    const float* pts = (const float*)d_in[1];
    const float* bb  = (const float*)d_in[2];
    float* out = (float*)d_out;

    int B = (int)(in_sizes[0] / (3 * G3));       // 16
    int N = in_sizes[1] / (3 * B);               // 200000

    int nchunk = (N + 255) / 256;                // 782
    long long total_blocks = (long long)B * nchunk * NSLAB;  // 100096
    trilerp_slab_kernel<<<(int)total_blocks, 256, 0, stream>>>(vel, pts, bb, out, N, nchunk);
}